// Round 11
// baseline (159.885 us; speedup 1.0000x reference)
//
#include <hip/hip_runtime.h>
#include <math.h>

#define C 128  // IN_C == OUT_C == 128

typedef _Float16 f16x8 __attribute__((ext_vector_type(8)));
typedef __attribute__((ext_vector_type(4))) float f32x4;

static __device__ __forceinline__ unsigned int pkh2(float lo, float hi) {
    unsigned short l = __builtin_bit_cast(unsigned short, (_Float16)lo);
    unsigned short h = __builtin_bit_cast(unsigned short, (_Float16)hi);
    return ((unsigned int)h << 16) | l;
}
static __device__ __forceinline__ float h2f_lo(unsigned int u) {
    return (float)__builtin_bit_cast(_Float16, (unsigned short)(u & 0xFFFFu));
}
static __device__ __forceinline__ float h2f_hi(unsigned int u) {
    return (float)__builtin_bit_cast(_Float16, (unsigned short)(u >> 16));
}
static __device__ __forceinline__ int dot4i8(unsigned int a, unsigned int b, int c) {
#if __has_builtin(__builtin_amdgcn_sdot4)
    return __builtin_amdgcn_sdot4(a, b, c, false);
#else
    c += (int)(signed char)(a & 0xff)         * (int)(signed char)(b & 0xff);
    c += (int)(signed char)((a >> 8) & 0xff)  * (int)(signed char)((b >> 8) & 0xff);
    c += (int)(signed char)((a >> 16) & 0xff) * (int)(signed char)((b >> 16) & 0xff);
    c += (int)(signed char)((a >> 24) & 0xff) * (int)(signed char)((b >> 24) & 0xff);
    return c;
#endif
}

// ---------------------------------------------------------------------------
// K_zero: one block zeroes the accumulation region (binCounts+amax+ssum+ssq)
// ---------------------------------------------------------------------------
__global__ __launch_bounds__(256) void k_zero(int* __restrict__ z, int n) {
    for (int i = threadIdx.x; i < n; i += 256) z[i] = 0;
}

// ---------------------------------------------------------------------------
// K_pre: fused [per-bin edge histogram] + [emb absmax reduction]
// ---------------------------------------------------------------------------
__global__ __launch_bounds__(256) void k_pre(const int* __restrict__ eidx,
                                             int* __restrict__ binCounts,
                                             const uint4* __restrict__ embv,
                                             int* __restrict__ amax,
                                             int E, int total4, int nEdgeBlocks) {
    __shared__ int lsh[256];
    const int t = threadIdx.x;
    if ((int)blockIdx.x < nEdgeBlocks) {
        lsh[t] = 0;
        __syncthreads();
        const int base = blockIdx.x * 2048;
#pragma unroll
        for (int j = 0; j < 8; ++j) {
            const int e = base + j * 256 + t;
            if (e < E) atomicAdd(&lsh[eidx[E + e] >> 8], 1);
        }
        __syncthreads();
        const int v = lsh[t];
        if (v) atomicAdd(&binCounts[t], v);
    } else {
        const int b = blockIdx.x - nEdgeBlocks;
        const int stride = ((int)gridDim.x - nEdgeBlocks) * 256;
        int m = 0;
        for (int i = b * 256 + t; i < total4; i += stride) {
            const uint4 v = embv[i];
            m = max(m, (int)(v.x & 0x7fffffffu));
            m = max(m, (int)(v.y & 0x7fffffffu));
            m = max(m, (int)(v.z & 0x7fffffffu));
            m = max(m, (int)(v.w & 0x7fffffffu));
        }
        lsh[t] = m;
        __syncthreads();
        for (int o = 128; o > 0; o >>= 1) {
            if (t < o) lsh[t] = max(lsh[t], lsh[t + o]);
            __syncthreads();
        }
        if (t == 0) atomicMax(amax, lsh[0]);   // positive-float-as-int compare
    }
}

// ---------------------------------------------------------------------------
// K0: emb f32 -> i8 (scale 126/absmax, never clamps); W f32 -> f16.
// One thread = 8 elems.
// ---------------------------------------------------------------------------
__global__ __launch_bounds__(256) void k_cast(const float* __restrict__ embf,
                                              unsigned int* __restrict__ embq,
                                              const float* __restrict__ Wf,
                                              unsigned int* __restrict__ Wh,
                                              const int* __restrict__ amax,
                                              int totalA8, int totalB8) {
    int i = blockIdx.x * 256 + threadIdx.x;
    if (i < totalA8) {
        const float s = 126.0f / fmaxf(__int_as_float(*amax), 1e-20f);
        const float4 a = ((const float4*)embf)[i * 2];
        const float4 b = ((const float4*)embf)[i * 2 + 1];
        int q[8];
        q[0] = __float2int_rn(a.x * s); q[1] = __float2int_rn(a.y * s);
        q[2] = __float2int_rn(a.z * s); q[3] = __float2int_rn(a.w * s);
        q[4] = __float2int_rn(b.x * s); q[5] = __float2int_rn(b.y * s);
        q[6] = __float2int_rn(b.z * s); q[7] = __float2int_rn(b.w * s);
        uint2 o;
        o.x = (unsigned)(q[0] & 255) | ((unsigned)(q[1] & 255) << 8) |
              ((unsigned)(q[2] & 255) << 16) | ((unsigned)(q[3] & 255) << 24);
        o.y = (unsigned)(q[4] & 255) | ((unsigned)(q[5] & 255) << 8) |
              ((unsigned)(q[6] & 255) << 16) | ((unsigned)(q[7] & 255) << 24);
        ((uint2*)embq)[i] = o;
    } else {
        i -= totalA8;
        if (i >= totalB8) return;
        const float4 a = ((const float4*)Wf)[i * 2];
        const float4 b = ((const float4*)Wf)[i * 2 + 1];
        uint4 o;
        o.x = pkh2(a.x, a.y); o.y = pkh2(a.z, a.w);
        o.z = pkh2(b.x, b.y); o.w = pkh2(b.z, b.w);
        ((uint4*)Wh)[i] = o;
    }
}

// ---------------------------------------------------------------------------
// K1: xl = x @ W^T via MFMA f16. Block = 4 waves, 64 rows (16/wave).
// ---------------------------------------------------------------------------
__global__ __launch_bounds__(256) void k_gemm(const float* __restrict__ x,
                                              const uint4* __restrict__ wb,
                                              unsigned short* __restrict__ xlh, int N) {
    const int lane = threadIdx.x & 63;
    const int wave = threadIdx.x >> 6;
    const int row0 = blockIdx.x * 64 + wave * 16;
    const int r = lane & 15, kg = lane >> 4;

    int arow = row0 + r;
    if (arow >= N) arow = N - 1;          // clamp (stores are guarded)
    const float* xrow = x + (size_t)arow * C;
    f16x8 A[4];
#pragma unroll
    for (int kb = 0; kb < 4; ++kb) {
        const float4 p0 = ((const float4*)(xrow + kb * 32 + kg * 8))[0];
        const float4 p1 = ((const float4*)(xrow + kb * 32 + kg * 8))[1];
        f16x8 a;
        a[0] = (_Float16)p0.x; a[1] = (_Float16)p0.y;
        a[2] = (_Float16)p0.z; a[3] = (_Float16)p0.w;
        a[4] = (_Float16)p1.x; a[5] = (_Float16)p1.y;
        a[6] = (_Float16)p1.z; a[7] = (_Float16)p1.w;
        A[kb] = a;
    }

#pragma unroll
    for (int nt = 0; nt < 8; ++nt) {
        const uint4* wrow = wb + (size_t)(nt * 16 + r) * 16;
        f32x4 acc = {0.0f, 0.0f, 0.0f, 0.0f};
#pragma unroll
        for (int kb = 0; kb < 4; ++kb) {
            f16x8 B = __builtin_bit_cast(f16x8, wrow[kb * 4 + kg]);
            acc = __builtin_amdgcn_mfma_f32_16x16x32_f16(A[kb], B, acc, 0, 0, 0);
        }
        const int orow = row0 + kg * 4;
        const int ocol = nt * 16 + r;
#pragma unroll
        for (int i = 0; i < 4; ++i)
            if (orow + i < N)
                xlh[(size_t)(orow + i) * C + ocol] =
                    __builtin_bit_cast(unsigned short, (_Float16)acc[i]);
    }
}

// ---------------------------------------------------------------------------
// CSR build (bucket sort). Bin = dst>>8. Record u32: [31:24]=dst&255,
// [23:0]=src (needs N < 2^24).
// ---------------------------------------------------------------------------
__global__ __launch_bounds__(256) void k_binscan(const int* __restrict__ binCounts,
                                                 int* __restrict__ binOffs,
                                                 int* __restrict__ binCursor, int NB) {
    __shared__ int ts[256];
    const int t = threadIdx.x;
    const int v = (t < NB) ? binCounts[t] : 0;
    ts[t] = v;
    __syncthreads();
    for (int o = 1; o < 256; o <<= 1) {
        int u = (t >= o) ? ts[t - o] : 0;
        __syncthreads();
        ts[t] += u;
        __syncthreads();
    }
    const int excl = ts[t] - v;
    if (t <= NB) binOffs[t] = excl;     // binOffs[NB] = E
    if (t < NB) binCursor[t] = excl;
}

__global__ __launch_bounds__(256) void k_bin(const int* __restrict__ eidx,
                                             int* __restrict__ binCursor,
                                             unsigned int* __restrict__ binned, int E) {
    __shared__ int lh[256];
    __shared__ int lb[256];
    const int t = threadIdx.x;
    lh[t] = 0;
    __syncthreads();
    const int base = blockIdx.x * 2048;
    int bj[8], rj[8];
    unsigned int recj[8];
#pragma unroll
    for (int j = 0; j < 8; ++j) {
        const int e = base + j * 256 + t;
        bj[j] = -1;
        if (e < E) {
            const int s = eidx[e];
            const int d = eidx[E + e];
            bj[j] = d >> 8;
            recj[j] = ((unsigned)(d & 255) << 24) | (unsigned)s;
            rj[j] = atomicAdd(&lh[bj[j]], 1);
        }
    }
    __syncthreads();
    const int c = lh[t];
    if (c) lb[t] = atomicAdd(&binCursor[t], c);
    __syncthreads();
#pragma unroll
    for (int j = 0; j < 8; ++j) {
        if (bj[j] >= 0) binned[lb[bj[j]] + rj[j]] = recj[j];
    }
}

__global__ __launch_bounds__(256) void k_place(const unsigned int* __restrict__ binned,
                                               const int* __restrict__ binOffs,
                                               int* __restrict__ offs,
                                               int* __restrict__ src_s,
                                               int N, int E) {
    __shared__ int cnt[256];
    __shared__ int ts[256];
    __shared__ int cur[256];
    const int b = blockIdx.x;
    const int t = threadIdx.x;
    const int node0 = b * 256;
    const int r0 = binOffs[b], r1 = binOffs[b + 1];
    cnt[t] = 0;
    __syncthreads();
    for (int i = r0 + t; i < r1; i += 256)
        atomicAdd(&cnt[binned[i] >> 24], 1);
    __syncthreads();
    const int v = cnt[t];
    ts[t] = v;
    __syncthreads();
    for (int o = 1; o < 256; o <<= 1) {
        int u = (t >= o) ? ts[t - o] : 0;
        __syncthreads();
        ts[t] += u;
        __syncthreads();
    }
    const int excl = r0 + ts[t] - v;
    if (node0 + t < N) offs[node0 + t] = excl;
    cur[t] = excl;
    __syncthreads();
    for (int i = r0 + t; i < r1; i += 256) {
        const unsigned int rec = binned[i];
        const int pos = atomicAdd(&cur[rec >> 24], 1);
        src_s[pos] = (int)(rec & 0xFFFFFFu);
    }
    if (b == 0 && t == 0) offs[N] = E;
}

// ---------------------------------------------------------------------------
// K4: fused attention + online softmax + aggregation. One wave per node,
// 8 edges/iter, 8-lane group dots.
// Cold path: i8 dot (4x v_dot4, 128B/edge gather; 6.4MB table ~ L2-resident)
// feeding only the (exactly accumulated) denominator. Certificate: scale
// q = amax/126 never clamps, so |a_true - a_i8*q^2| <= q^2*16288 =: DELTA.
// Hot test (a_i8*q^2 + DELTA > m - 28) over-covers: cold edges provably
// have weight < e^-28 (below fp32 ulp of the output sum). Hot edges take
// the exact f32 path: re-gather emb rows, exact dot, max rescale, xl
// gather when w > 1e-12. Self logit exact f32 (it is the max for sane data;
// if quantization degenerates, ALL edges turn hot and the kernel reduces
// to the exact algorithm).
// ---------------------------------------------------------------------------
__global__ __launch_bounds__(256) void k_agg(const unsigned int* __restrict__ xlh,
                                             const float* __restrict__ emb,
                                             const uint4* __restrict__ embq4,
                                             const int* __restrict__ src_s,
                                             const int* __restrict__ offs,
                                             const float* __restrict__ bias,
                                             const int* __restrict__ amax,
                                             float* __restrict__ out, int N) {
    const int node = (int)((blockIdx.x * (size_t)blockDim.x + threadIdx.x) >> 6);
    const int lane = threadIdx.x & 63;
    if (node >= N) return;
    const int g = lane >> 3;        // edge slot 0..7
    const int sl = lane & 7;        // sub-lane within 8-group
    const int s0 = offs[node], s1 = offs[node + 1];

    const float maxabs = fmaxf(__int_as_float(*amax), 1e-20f);
    const float qs = maxabs / 126.0f;
    const float q2 = qs * qs;
    const float DELTA = q2 * 16288.0f + 1.0f;   // worst-case i8 err + slack

    // self logit = ||emb[node]||^2, exact f32 (lane covers dims [sl*16,+16))
    float m;
    {
        const float4* er = (const float4*)(emb + (size_t)node * C) + sl * 4;
        float p = 0.0f;
#pragma unroll
        for (int k = 0; k < 4; ++k) {
            const float4 v = er[k];
            p = fmaf(v.x, v.x, p); p = fmaf(v.y, v.y, p);
            p = fmaf(v.z, v.z, p); p = fmaf(v.w, v.w, p);
        }
        p += __shfl_xor(p, 4); p += __shfl_xor(p, 2); p += __shfl_xor(p, 1);
        m = p;                       // running max (self included)
    }

    float wself = 1.0f;   // exp(self - m)
    float dex = 0.0f;     // hot-path denominator (wave-uniform)
    float dpart = 0.0f;   // per-group cold denominator partial
    const unsigned int xw = xlh[(size_t)node * (C / 2) + lane];
    float2 acc = {h2f_lo(xw), h2f_hi(xw)};   // wself * xl[node]

    const uint4 qd = embq4[(size_t)node * 8 + sl];

    for (int base = s0; base < s1; base += 8) {
        int mys = -1;
        if (lane < 8 && base + lane < s1) mys = src_s[base + lane];
        const int sg = __shfl(mys, g);
        const int sa = (sg >= 0) ? sg : node;

        const uint4 qv = embq4[(size_t)sa * 8 + sl];
        int ai = dot4i8(qv.x, qd.x, 0);
        ai = dot4i8(qv.y, qd.y, ai);
        ai = dot4i8(qv.z, qd.z, ai);
        ai = dot4i8(qv.w, qd.w, ai);
        ai += __shfl_xor(ai, 4); ai += __shfl_xor(ai, 2); ai += __shfl_xor(ai, 1);
        const float af = (float)ai * q2;

        const bool valid = sg >= 0;
        const bool hot = valid && (af + DELTA > m - 28.0f);
        if (__any(hot)) {
            const unsigned long long bal = __ballot(hot);
#pragma unroll 1
            for (int j = 0; j < 8; ++j) {
                if (!((bal >> (j * 8)) & 1ULL)) continue;
                const int sj = __shfl(mys, j);
                // exact f32 dot: emb[node] . emb[sj]
                const float4* dr = (const float4*)(emb + (size_t)node * C) + sl * 4;
                const float4* sr = (const float4*)(emb + (size_t)sj * C) + sl * 4;
                float ax = 0.0f;
#pragma unroll
                for (int k = 0; k < 4; ++k) {
                    const float4 dv = dr[k];
                    const float4 sv = sr[k];
                    ax = fmaf(dv.x, sv.x, ax); ax = fmaf(dv.y, sv.y, ax);
                    ax = fmaf(dv.z, sv.z, ax); ax = fmaf(dv.w, sv.w, ax);
                }
                ax += __shfl_xor(ax, 4); ax += __shfl_xor(ax, 2); ax += __shfl_xor(ax, 1);
                if (ax > m) {            // wave-uniform rescale
                    const float cs = __expf(m - ax);
                    dpart *= cs; dex *= cs; wself *= cs;
                    acc.x *= cs; acc.y *= cs;
                    m = ax;
                }
                const float w = __expf(ax - m);
                dex += w;
                if (w > 1e-12f) {
                    const unsigned int u = xlh[(size_t)sj * (C / 2) + lane];
                    acc.x = fmaf(w, h2f_lo(u), acc.x);
                    acc.y = fmaf(w, h2f_hi(u), acc.y);
                }
            }
        }
        // cold groups: denominator contribution only, no further gathers
        dpart += (valid && !hot) ? __expf(af - m) : 0.0f;
    }

    // sum the 8 per-group partials (lanes within a group hold identical dpart)
    float dg = dpart;
    dg += __shfl_xor(dg, 8); dg += __shfl_xor(dg, 16); dg += __shfl_xor(dg, 32);
    const float dtot = wself + dex + dg;
    const float inv = 1.0f / (dtot + 1e-16f);
    const int c = lane * 2;
    float2 o2;
    o2.x = fmaf(acc.x, inv, bias[c]);
    o2.y = fmaf(acc.y, inv, bias[c + 1]);
    ((float2*)(out + (size_t)node * C))[lane] = o2;
}

// ---------------------------------------------------------------------------
// K5: BN stats — grid-stride float4; fixed channel quad per thread.
// ---------------------------------------------------------------------------
__global__ __launch_bounds__(256) void k_bnstats(const float* __restrict__ out,
                                                 float* __restrict__ ssum,
                                                 float* __restrict__ ssq, int N) {
    const int tid = threadIdx.x;
    const int total4 = N * (C / 4);
    const int stride = gridDim.x * 256;          // multiple of 32
    float4 s4 = {0, 0, 0, 0}, q4 = {0, 0, 0, 0};
    for (int i = blockIdx.x * 256 + tid; i < total4; i += stride) {
        float4 v = ((const float4*)out)[i];
        s4.x += v.x; s4.y += v.y; s4.z += v.z; s4.w += v.w;
        q4.x = fmaf(v.x, v.x, q4.x); q4.y = fmaf(v.y, v.y, q4.y);
        q4.z = fmaf(v.z, v.z, q4.z); q4.w = fmaf(v.w, v.w, q4.w);
    }
    __shared__ float4 lsum[256];
    __shared__ float4 lsq[256];
    lsum[tid] = s4; lsq[tid] = q4;
    __syncthreads();
    if (tid < 32) {
        float4 S = lsum[tid], Q = lsq[tid];
#pragma unroll
        for (int j = 1; j < 8; ++j) {
            float4 a = lsum[tid + 32 * j], b = lsq[tid + 32 * j];
            S.x += a.x; S.y += a.y; S.z += a.z; S.w += a.w;
            Q.x += b.x; Q.y += b.y; Q.z += b.z; Q.w += b.w;
        }
        const int c = tid * 4;
        atomicAdd(&ssum[c], S.x);     atomicAdd(&ssum[c + 1], S.y);
        atomicAdd(&ssum[c + 2], S.z); atomicAdd(&ssum[c + 3], S.w);
        atomicAdd(&ssq[c], Q.x);      atomicAdd(&ssq[c + 1], Q.y);
        atomicAdd(&ssq[c + 2], Q.z);  atomicAdd(&ssq[c + 3], Q.w);
    }
}

// ---------------------------------------------------------------------------
// K6: in-place BN apply (training-mode batch stats, biased var) + ReLU
// ---------------------------------------------------------------------------
__global__ __launch_bounds__(256) void k_bnapply(float* __restrict__ out,
                                                 const float* __restrict__ ssum,
                                                 const float* __restrict__ ssq,
                                                 const float* __restrict__ gamma,
                                                 const float* __restrict__ beta,
                                                 int N) {
    const int idx = blockIdx.x * blockDim.x + threadIdx.x;   // float4 index
    const int total = N * (C / 4);
    if (idx >= total) return;
    const int c = (idx * 4) & 127;
    float4 v = ((const float4*)out)[idx];
    const float invN = 1.0f / (float)N;
    float r[4] = {v.x, v.y, v.z, v.w};
#pragma unroll
    for (int j = 0; j < 4; ++j) {
        float mu = ssum[c + j] * invN;
        float var = fmaf(-mu, mu, ssq[c + j] * invN);
        var = fmaxf(var, 0.0f);
        float sc = gamma[c + j] / sqrtf(var + 1e-5f);
        float val = fmaf(r[j] - mu, sc, beta[c + j]);
        r[j] = fmaxf(val, 0.0f);
    }
    float4 o = {r[0], r[1], r[2], r[3]};
    ((float4*)out)[idx] = o;
}

// ---------------------------------------------------------------------------
extern "C" void kernel_launch(void* const* d_in, const int* in_sizes, int n_in,
                              void* d_out, int out_size, void* d_ws, size_t ws_size,
                              hipStream_t stream) {
    const float* x     = (const float*)d_in[0];
    const int*   eidx  = (const int*)d_in[1];   // [2][E]
    const float* emb   = (const float*)d_in[2];
    const float* W     = (const float*)d_in[3];
    const float* bias  = (const float*)d_in[4];
    const float* gamma = (const float*)d_in[5];
    const float* beta  = (const float*)d_in[6];
    const int N = in_sizes[0] / C;
    const int E = in_sizes[1] / 2;
    float* out = (float*)d_out;

    char* ws = (char*)d_ws;
    size_t off = 0;
    auto alloc = [&](size_t bytes) -> void* {
        void* p = ws + off;
        off = (off + bytes + 255) & ~(size_t)255;
        return p;
    };
    unsigned short* xlh  = (unsigned short*)alloc((size_t)N * C * 2);
    unsigned int*   embq = (unsigned int*)  alloc((size_t)N * C);       // i8
    unsigned int*   wh   = (unsigned int*)  alloc((size_t)C * C * 2);
    int*   src_s    = (int*)  alloc((size_t)E * 4);
    unsigned int* binned = (unsigned int*)alloc((size_t)E * 4);
    int*   offs     = (int*)  alloc((size_t)(N + 1) * 4);
    int*   binOffs  = (int*)  alloc(257 * 4);
    int*   binCur   = (int*)  alloc(256 * 4);
    // contiguous zero-init region: binCounts + amax + ssum + ssq
    char*  zbase    = (char*)alloc(0);
    int*   binCounts= (int*)  alloc(256 * 4);
    int*   amax     = (int*)  alloc(4);
    float* ssum     = (float*)alloc(C * 4);
    float* ssq      = (float*)alloc(C * 4);
    size_t zbytes   = (char*)ws + off - zbase;

    const int NB = (N + 255) / 256;              // 196 bins (<= 255)
    const int nEdgeBlocks = (E + 2047) / 2048;   // 391
    const int embTot8 = N * (C / 8);
    const int wTot8   = C * (C / 8);
    const int embTot4 = N * (C / 4);

    k_zero   <<<1,               256, 0, stream>>>((int*)zbase, (int)(zbytes / 4));
    k_pre    <<<nEdgeBlocks + 256, 256, 0, stream>>>(
                 eidx, binCounts, (const uint4*)emb, amax, E, embTot4, nEdgeBlocks);
    k_cast   <<<(embTot8 + wTot8 + 255) / 256, 256, 0, stream>>>(
                 emb, embq, W, wh, amax, embTot8, wTot8);
    k_gemm   <<<(N + 63) / 64,   256, 0, stream>>>(x, (const uint4*)wh, xlh, N);
    k_binscan<<<1,               256, 0, stream>>>(binCounts, binOffs, binCur, NB);
    k_bin    <<<nEdgeBlocks,     256, 0, stream>>>(eidx, binCur, binned, E);
    k_place  <<<NB,              256, 0, stream>>>(binned, binOffs, offs, src_s, N, E);
    k_agg    <<<(int)(((size_t)N * 64 + 255) / 256), 256, 0, stream>>>(
                 (const unsigned int*)xlh, emb, (const uint4*)embq,
                 src_s, offs, bias, amax, out, N);
    k_bnstats<<<256,             256, 0, stream>>>(out, ssum, ssq, N);
    k_bnapply<<<(N * (C / 4) + 255) / 256, 256, 0, stream>>>(out, ssum, ssq, gamma, beta, N);
}